// Round 9
// baseline (4822.738 us; speedup 1.0000x reference)
//
#include <hip/hip_runtime.h>
#include <hip/hip_bf16.h>
#include <math.h>

#define Bz 64
#define Tz 256
#define Dz 512
#define Hz 1024
#define G3 3072
#define NBK 64      // blocks in persistent recurrence kernel

typedef short bf16x8 __attribute__((ext_vector_type(8)));
typedef float f32x4 __attribute__((ext_vector_type(4)));

__device__ __forceinline__ float sigm(float x){ return 1.0f/(1.0f+expf(-x)); }

__device__ __forceinline__ unsigned short f2b(float f){
  union{float f;unsigned u;}v; v.f=f;
  unsigned r = v.u + 0x7FFFu + ((v.u>>16)&1u);
  return (unsigned short)(r>>16);
}
__device__ __forceinline__ float b2f(unsigned short s){
  union{unsigned u;float f;}v; v.u = ((unsigned)s)<<16; return v.f;
}
__device__ __forceinline__ unsigned pk2(float a, float b){
  return (unsigned)f2b(a) | ((unsigned)f2b(b)<<16);
}

// ---- coherence protocol (rounds 5/6/8 lessons) ----
// PRODUCER: shared-state writes via relaxed sc1 atomic stores (bypass L1/L2,
//   land at memory-side LLC; nothing dirty anywhere). __syncthreads drains
//   vmcnt, then tid0 stores the flag relaxed. (r5/r8-proven)
// CONSUMER: relaxed poll, NO acquire-inv. All cross-step shared-state reads
//   bypass L1/L2: bulk B-operands via inline-asm global_load_dwordx4 sc0 sc1
//   (coalesced 16B/lane, direct LLC); small hF/iT reads via 8B relaxed
//   agent atomics (r5-proven fresh). Plain cached reads only for immutable
//   data (igT, weights). -> no inv scan, no stale lines possible.
__device__ __forceinline__ unsigned long long cld64(const void* p){
  return __hip_atomic_load((const unsigned long long*)p, __ATOMIC_RELAXED, __HIP_MEMORY_SCOPE_AGENT);
}
__device__ __forceinline__ void cst64(void* p, unsigned long long v){
  __hip_atomic_store((unsigned long long*)p, v, __ATOMIC_RELAXED, __HIP_MEMORY_SCOPE_AGENT);
}
__device__ __forceinline__ float2 cldf2(const float* p){
  union { unsigned long long u; float2 f; } U; U.u = cld64(p); return U.f;
}
__device__ __forceinline__ void cstf2(float* p, float a, float b){
  union { unsigned long long u; float2 f; } U; U.f = make_float2(a,b); cst64(p, U.u);
}
__device__ __forceinline__ int cld32(const int* p){
  return __hip_atomic_load(p, __ATOMIC_RELAXED, __HIP_MEMORY_SCOPE_AGENT);
}
__device__ __forceinline__ void cst32(int* p, int v){
  __hip_atomic_store(p, v, __ATOMIC_RELAXED, __HIP_MEMORY_SCOPE_AGENT);
}
__device__ __forceinline__ void waitcan(const int* can, int tgt){
  int l = threadIdx.x & 63;
  while (!__all(cld32(can + l) >= tgt))
    __builtin_amdgcn_s_sleep(1);
  asm volatile("" ::: "memory");
}

// ---------------- f32 skinny GEMM core (kP only, tiny) ----------------
#define KCHUNK 128
#define LDA 132
template<int COLS, int KDIM>
__device__ __forceinline__ void gemm_core(const float* __restrict__ Abase, int rowStride,
                                          const float* __restrict__ W,
                                          int jc0, int b, int tid,
                                          float* __restrict__ acc, float* __restrict__ lds)
{
#pragma unroll
  for (int c=0;c<COLS;c++) acc[c]=0.0f;
  constexpr int C4 = KCHUNK/4;
  for (int kb=0; kb<KDIM; kb+=KCHUNK) {
    __syncthreads();
    for (int i = tid; i < Bz*C4; i += 256) {
      int r  = i / C4;
      int c4 = i % C4;
      float4 v = *(const float4*)(Abase + (size_t)r*rowStride + kb + c4*4);
      *(float4*)(lds + r*LDA + c4*4) = v;
    }
    __syncthreads();
    const float* arow  = lds + b*LDA;
    const float* wbase = W + (size_t)jc0*KDIM + kb;
    for (int k=0;k<KCHUNK;k+=4) {
      float4 a = *(const float4*)(arow + k);
#pragma unroll
      for (int c=0;c<COLS;c++) {
        float4 w = *(const float4*)(wbase + (size_t)c*KDIM + k);
        acc[c] = fmaf(a.x,w.x,fmaf(a.y,w.y,fmaf(a.z,w.z,fmaf(a.w,w.w,acc[c]))));
      }
    }
  }
}

// ---- kP: pT[j][b] = ctx[b]·Wp[j] + bp[j] + bi[j] + (j<2H ? bh[j] : bc[j-2H])
__global__ __launch_bounds__(256)
void kP(const float* __restrict__ ctx, const float* __restrict__ Wp,
        const float* __restrict__ bp, const float* __restrict__ bh,
        const float* __restrict__ bc, const float* __restrict__ bi,
        float* __restrict__ pT)
{
  __shared__ float lds[Bz*LDA];
  int tid=threadIdx.x; int b=tid&63;
  int wv=__builtin_amdgcn_readfirstlane(tid>>6);
  int jc0 = blockIdx.x*16 + wv*4;
  float acc[4];
  gemm_core<4, Hz>(ctx, Hz, Wp, jc0, b, tid, acc, lds);
#pragma unroll
  for(int c=0;c<4;c++){
    int j=jc0+c;
    float v = acc[c] + bp[j] + bi[j] + (j < 2*Hz ? bh[j] : bc[j-2*Hz]);
    pT[(size_t)j*64 + b] = v;
  }
}

// ---- kI: hF quad-layout init + hB bf16 init (parity-0 buffers). 64 blocks x 256 thr.
// hF quad layout: hF[((j>>2)*64 + b)*4 + (j&3)]
__global__ __launch_bounds__(256)
void kI(const float* __restrict__ h0, float* __restrict__ hF, unsigned short* __restrict__ hB)
{
  int b = blockIdx.x;
  int j = threadIdx.x*4;
  float4 v = *(const float4*)(h0 + (size_t)b*Hz + j);
  *(float4*)(hF + ((size_t)(j>>2)*64 + b)*4) = v;
  unsigned long long pk = (unsigned long long)pk2(v.x,v.y)
                        | ((unsigned long long)pk2(v.z,v.w) << 32);
  *(unsigned long long*)(hB + (size_t)b*Hz + j) = pk;
}

// ---- kAm: MFMA input GEMM. igT[t][j][b] = bf16( x[b,t]·Wi[j] + pT[j][b] )
__global__ __launch_bounds__(1024)
void kAm(const float* __restrict__ x, const float* __restrict__ Wi,
         const float* __restrict__ pT, unsigned short* __restrict__ igT)
{
  __shared__ unsigned short wiF[4*16*64*8];  // 64 KB
  __shared__ unsigned short xs[64*528];      // 66 KB
  __shared__ unsigned short igs[64*64];      // 8 KB
  const int tid = threadIdx.x;
  const int lane = tid & 63;
  const int w = __builtin_amdgcn_readfirstlane(tid >> 6);
  const int j0 = blockIdx.x * 64;
  const int t0 = blockIdx.y * 16;
  const int mt = w >> 2, nt = w & 3;
  const int bb = nt*16 + (lane & 15);
  const int q  = lane >> 4;
  const int jl = mt*16 + q*4;

  for (int idx = tid; idx < 4096; idx += 1024) {
    int mt2 = idx >> 10;
    int ks = (idx >> 6) & 15;
    int ln = idx & 63;
    int j = j0 + mt2*16 + (ln & 15);
    int k = ks*32 + (ln >> 4)*8;
    const float* s = Wi + (size_t)j*Dz + k;
    unsigned short* d = wiF + (size_t)idx*8;
#pragma unroll
    for (int qq=0;qq<8;qq++) d[qq] = f2b(s[qq]);
  }
  float pv[4];
#pragma unroll
  for (int r=0;r<4;r++) pv[r] = pT[(size_t)(j0+jl+r)*64 + bb];

  for (int it=0; it<16; it++) {
    int t = t0 + it;
    __syncthreads();
    for (int i = tid; i < 64*32; i += 1024) {
      int b = i >> 5, c = i & 31;
      const float* s = x + ((size_t)b*Tz + t)*Dz + c*16;
      unsigned* d = (unsigned*)(xs + (size_t)b*528 + c*16);
      float4 v0 = *(const float4*)(s);
      float4 v1 = *(const float4*)(s+4);
      float4 v2 = *(const float4*)(s+8);
      float4 v3 = *(const float4*)(s+12);
      d[0]=pk2(v0.x,v0.y); d[1]=pk2(v0.z,v0.w);
      d[2]=pk2(v1.x,v1.y); d[3]=pk2(v1.z,v1.w);
      d[4]=pk2(v2.x,v2.y); d[5]=pk2(v2.z,v2.w);
      d[6]=pk2(v3.x,v3.y); d[7]=pk2(v3.z,v3.w);
    }
    __syncthreads();
    f32x4 acc = {0.f,0.f,0.f,0.f};
    const unsigned short* bsrc = xs + (size_t)bb*528 + q*8;
#pragma unroll
    for (int ks=0; ks<16; ks++) {
      bf16x8 a = *(const bf16x8*)(wiF + ((size_t)(mt*16+ks)*64 + lane)*8);
      bf16x8 b = *(const bf16x8*)(bsrc + ks*32);
      acc = __builtin_amdgcn_mfma_f32_16x16x32_bf16(a, b, acc, 0, 0, 0);
    }
#pragma unroll
    for (int r=0;r<4;r++) igs[(size_t)(jl+r)*64 + bb] = f2b(acc[r] + pv[r]);
    __syncthreads();
    if (tid < 512) {
      int j = tid >> 3, seg = tid & 7;
      *(uint4*)(igT + ((size_t)t*G3 + j0 + j)*64 + seg*8) =
        *(const uint4*)(igs + (size_t)j*64 + seg*8);
    }
  }
}

// ---- krec: persistent MFMA recurrence, 64 blocks x 1024 threads.
// Canary sync + LLC-direct consumer reads (no acquire-inv — see protocol above).
// canP[n]=t+1 after phase1@t (rhB/iT ready); canH[n]=t+1 after phase2@t (h_{t+1}).
// Phase1@t waits canH>=t; phase2@t waits canP>=t+1. hF/hB parity double-buffered;
// rhB/iT single-buffered (WAR via the canH/canP chain; max skew < 1 round).
__global__ __launch_bounds__(1024)
void krec(const float* __restrict__ Wh, const float* __restrict__ Wc,
          const unsigned short* __restrict__ igT,
          float* __restrict__ hF0, float* __restrict__ hF1,
          unsigned short* __restrict__ hB0, unsigned short* __restrict__ hB1,
          unsigned short* __restrict__ rhB, float* __restrict__ iT,
          float* __restrict__ out, int* canP, int* canH)
{
  __shared__ unsigned short whF[2*32*64*8];  // 64 KB
  __shared__ unsigned short wcF[32*64*8];    // 32 KB
  __shared__ float red[16*64*4];             // 16 KB
  const int tid = threadIdx.x;
  const int lane = tid & 63;
  const int w = __builtin_amdgcn_readfirstlane(tid >> 6);
  const int n = blockIdx.x;

  // fragment-swizzle weight slices (f32 -> bf16), one-time
  for (int idx = tid; idx < 4096; idx += 1024) {
    int mt = idx >> 11;
    int ks = (idx >> 6) & 31;
    int ln = idx & 63;
    int j = n*32 + mt*16 + (ln & 15);
    int k = ks*32 + (ln >> 4)*8;
    const float* s = Wh + (size_t)j*Hz + k;
    unsigned short* d = whF + (size_t)idx*8;
#pragma unroll
    for (int qq=0;qq<8;qq++) d[qq] = f2b(s[qq]);
  }
  for (int idx = tid; idx < 2048; idx += 1024) {
    int ks = (idx >> 6) & 31;
    int ln = idx & 63;
    int j = n*16 + (ln & 15);
    int k = ks*32 + (ln >> 4)*8;
    const float* s = Wc + (size_t)j*Hz + k;
    unsigned short* d = wcF + (size_t)idx*8;
#pragma unroll
    for (int qq=0;qq<8;qq++) d[qq] = f2b(s[qq]);
  }

  for (int t=0;t<Tz;t++) {
    const unsigned short* igt = igT + (size_t)t*G3*64;
    const unsigned short* hBr = (t&1) ? hB1 : hB0;
    unsigned short*       hBw = (t&1) ? hB0 : hB1;
    const float*          hFr = (t&1) ? hF1 : hF0;
    float*                hFw = (t&1) ? hF0 : hF1;
    // ---------- phase 1: gates r,i ----------
    {
      int tp = w & 7, kh = w >> 3;        // 8 tiles x split-K-2
      int mt = tp >> 2, nt = tp & 3;
      int bb = nt*16 + (lane & 15);
      int q  = lane >> 4;
      int jg = n*32 + mt*16 + q*4;        // gate col in [0,2048)
      float igv[4], hv[4];
      if (w < 8) {                        // igT prefetch: immutable data, plain cached
#pragma unroll
        for (int r=0;r<4;r++) igv[r] = b2f(igt[(size_t)(jg+r)*64 + bb]);
      }
      if (w == 0) waitcan(canH, t);       // h_t ready (all 64 producers)
      __syncthreads();
      if (w < 8 && n < 32) {
        const float* hp = hFr + ((size_t)(jg>>2)*64 + bb)*4;
        float2 a01 = cldf2(hp), a23 = cldf2(hp+2);   // LLC-direct (cross-block)
        hv[0]=a01.x; hv[1]=a01.y; hv[2]=a23.x; hv[3]=a23.y;
      }
      // B-operand: 16x global_load_dwordx4 sc0 sc1 (bypass L1/L2, read LLC),
      // issued together, one vmcnt(0) inside the asm block.
      bf16x8 bfr[16];
      {
        unsigned voff = (unsigned)(bb*2048 + q*16 + kh*1024);
        asm volatile(
          "global_load_dwordx4 %0, %16, %17 sc0 sc1\n\t"
          "global_load_dwordx4 %1, %16, %17 offset:64 sc0 sc1\n\t"
          "global_load_dwordx4 %2, %16, %17 offset:128 sc0 sc1\n\t"
          "global_load_dwordx4 %3, %16, %17 offset:192 sc0 sc1\n\t"
          "global_load_dwordx4 %4, %16, %17 offset:256 sc0 sc1\n\t"
          "global_load_dwordx4 %5, %16, %17 offset:320 sc0 sc1\n\t"
          "global_load_dwordx4 %6, %16, %17 offset:384 sc0 sc1\n\t"
          "global_load_dwordx4 %7, %16, %17 offset:448 sc0 sc1\n\t"
          "global_load_dwordx4 %8, %16, %17 offset:512 sc0 sc1\n\t"
          "global_load_dwordx4 %9, %16, %17 offset:576 sc0 sc1\n\t"
          "global_load_dwordx4 %10, %16, %17 offset:640 sc0 sc1\n\t"
          "global_load_dwordx4 %11, %16, %17 offset:704 sc0 sc1\n\t"
          "global_load_dwordx4 %12, %16, %17 offset:768 sc0 sc1\n\t"
          "global_load_dwordx4 %13, %16, %17 offset:832 sc0 sc1\n\t"
          "global_load_dwordx4 %14, %16, %17 offset:896 sc0 sc1\n\t"
          "global_load_dwordx4 %15, %16, %17 offset:960 sc0 sc1\n\t"
          "s_waitcnt vmcnt(0)"
          : "=v"(bfr[0]), "=v"(bfr[1]), "=v"(bfr[2]), "=v"(bfr[3]),
            "=v"(bfr[4]), "=v"(bfr[5]), "=v"(bfr[6]), "=v"(bfr[7]),
            "=v"(bfr[8]), "=v"(bfr[9]), "=v"(bfr[10]), "=v"(bfr[11]),
            "=v"(bfr[12]), "=v"(bfr[13]), "=v"(bfr[14]), "=v"(bfr[15])
          : "v"(voff), "s"(hBr)
          : "memory");
      }
      f32x4 acc = {0.f,0.f,0.f,0.f};
      const unsigned short* asrc = whF + ((size_t)(mt*32 + kh*16)*64 + lane)*8;
#pragma unroll
      for (int ks=0; ks<16; ks++) {
        bf16x8 a = *(const bf16x8*)(asrc + (size_t)ks*64*8);
        acc = __builtin_amdgcn_mfma_f32_16x16x32_bf16(a, bfr[ks], acc, 0, 0, 0);
      }
      *(f32x4*)(red + ((size_t)w*64 + lane)*4) = acc;
      __syncthreads();
      if (w < 8) {
        f32x4 o  = *(const f32x4*)(red + ((size_t)w*64+lane)*4);
        f32x4 p2 = *(const f32x4*)(red + ((size_t)(w+8)*64+lane)*4);
        if (n < 32) {
          unsigned long long pk = 0;
#pragma unroll
          for (int r=0;r<4;r++) {
            float g = sigm(o[r] + p2[r] + igv[r]);
            pk |= (unsigned long long)f2b(g * hv[r]) << (16*r);
          }
          cst64(rhB + (size_t)bb*Hz + jg, pk);        // sc1 bypass -> LLC
        } else {
          float g0 = sigm(o[0] + p2[0] + igv[0]);
          float g1 = sigm(o[1] + p2[1] + igv[1]);
          float g2 = sigm(o[2] + p2[2] + igv[2]);
          float g3 = sigm(o[3] + p2[3] + igv[3]);
          float* ip = iT + ((size_t)((jg-1024)>>2)*64 + bb)*4;
          cstf2(ip, g0, g1); cstf2(ip+2, g2, g3);     // sc1 bypass -> LLC
        }
      }
      __syncthreads();                    // vmcnt drained -> sc1 stores at LLC
      if (tid == 0) cst32(canP + n, t+1); // relaxed flag
    }
    // ---------- phase 2: n-gate + h update ----------
    {
      int nt = w & 3, kq = w >> 2;        // 4 tiles x split-K-4
      int bb = nt*16 + (lane & 15);
      int q  = lane >> 4;
      int jn = n*16 + q*4;                // col in [0,1024)
      float igv[4], hv[4], iv[4];
      if (w < 4) {                        // igT prefetch: immutable, plain cached
#pragma unroll
        for (int r=0;r<4;r++) igv[r] = b2f(igt[(size_t)(2048+jn+r)*64 + bb]);
      }
      if (w == 0) waitcan(canP, t+1);     // rhB_t + iT_t ready (all 64 producers)
      __syncthreads();
      if (w < 4) {
        const float* hp = hFr + ((size_t)(jn>>2)*64 + bb)*4;
        float2 a01 = cldf2(hp), a23 = cldf2(hp+2);   // LLC-direct (own sc1 data)
        hv[0]=a01.x; hv[1]=a01.y; hv[2]=a23.x; hv[3]=a23.y;
        const float* ip = iT + ((size_t)(jn>>2)*64 + bb)*4;
        float2 b01 = cldf2(ip), b23 = cldf2(ip+2);   // LLC-direct (cross-block)
        iv[0]=b01.x; iv[1]=b01.y; iv[2]=b23.x; iv[3]=b23.y;
      }
      bf16x8 bfr[8];
      {
        unsigned voff = (unsigned)(bb*2048 + q*16 + kq*512);
        asm volatile(
          "global_load_dwordx4 %0, %8, %9 sc0 sc1\n\t"
          "global_load_dwordx4 %1, %8, %9 offset:64 sc0 sc1\n\t"
          "global_load_dwordx4 %2, %8, %9 offset:128 sc0 sc1\n\t"
          "global_load_dwordx4 %3, %8, %9 offset:192 sc0 sc1\n\t"
          "global_load_dwordx4 %4, %8, %9 offset:256 sc0 sc1\n\t"
          "global_load_dwordx4 %5, %8, %9 offset:320 sc0 sc1\n\t"
          "global_load_dwordx4 %6, %8, %9 offset:384 sc0 sc1\n\t"
          "global_load_dwordx4 %7, %8, %9 offset:448 sc0 sc1\n\t"
          "s_waitcnt vmcnt(0)"
          : "=v"(bfr[0]), "=v"(bfr[1]), "=v"(bfr[2]), "=v"(bfr[3]),
            "=v"(bfr[4]), "=v"(bfr[5]), "=v"(bfr[6]), "=v"(bfr[7])
          : "v"(voff), "s"(rhB)
          : "memory");
      }
      f32x4 acc = {0.f,0.f,0.f,0.f};
#pragma unroll
      for (int ks=0; ks<8; ks++) {
        bf16x8 a = *(const bf16x8*)(wcF + ((size_t)(kq*8+ks)*64 + lane)*8);
        acc = __builtin_amdgcn_mfma_f32_16x16x32_bf16(a, bfr[ks], acc, 0, 0, 0);
      }
      *(f32x4*)(red + ((size_t)w*64 + lane)*4) = acc;
      __syncthreads();
      if (w < 4) {
        f32x4 s0 = *(const f32x4*)(red + ((size_t)w*64+lane)*4);
        f32x4 s1 = *(const f32x4*)(red + ((size_t)(w+4)*64+lane)*4);
        f32x4 s2 = *(const f32x4*)(red + ((size_t)(w+8)*64+lane)*4);
        f32x4 s3 = *(const f32x4*)(red + ((size_t)(w+12)*64+lane)*4);
        float hy4[4];
        unsigned long long pk = 0;
#pragma unroll
        for (int r=0;r<4;r++) {
          float g  = s0[r]+s1[r]+s2[r]+s3[r] + igv[r];
          float ng = tanhf(g);
          float hy = hv[r] + iv[r]*(ng - hv[r]);
          hy4[r] = hy;
          pk |= (unsigned long long)f2b(hy) << (16*r);
        }
        float* hp = hFw + ((size_t)(jn>>2)*64 + bb)*4;
        cstf2(hp,   hy4[0], hy4[1]);                  // sc1 bypass -> LLC
        cstf2(hp+2, hy4[2], hy4[3]);
        cst64(hBw + (size_t)bb*Hz + jn, pk);          // sc1 bypass -> LLC
        float4 ov; ov.x=hy4[0]; ov.y=hy4[1]; ov.z=hy4[2]; ov.w=hy4[3];
        *(float4*)(out + ((size_t)bb*Tz + t)*Hz + jn) = ov;  // plain (host-only)
      }
      __syncthreads();                    // vmcnt drained -> sc1 stores at LLC
      if (tid == 0) cst32(canH + n, t+1); // relaxed flag
    }
  }
}

// ---- final hidden state: hN[b][j] = hF(quad)[j][b]
__global__ __launch_bounds__(256)
void ktr(const float* __restrict__ hF, float* __restrict__ hN)
{
  int b = blockIdx.x;
  int j = threadIdx.x*4;
  float4 v = *(const float4*)(hF + ((size_t)(j>>2)*64 + b)*4);
  *(float4*)(hN + (size_t)b*Hz + j) = v;
}

extern "C" void kernel_launch(void* const* d_in, const int* in_sizes, int n_in,
                              void* d_out, int out_size, void* d_ws, size_t ws_size,
                              hipStream_t stream)
{
  const float* x   = (const float*)d_in[0];
  const float* h0  = (const float*)d_in[1];
  const float* ctx = (const float*)d_in[2];
  const float* Wi  = (const float*)d_in[3];
  const float* bi  = (const float*)d_in[4];
  const float* Wh  = (const float*)d_in[5];
  const float* bh  = (const float*)d_in[6];
  const float* Wp  = (const float*)d_in[7];
  const float* bp  = (const float*)d_in[8];
  const float* Wc  = (const float*)d_in[9];
  const float* bc  = (const float*)d_in[10];
  float* out = (float*)d_out;

  char* wsp = (char*)d_ws;
  float* pT  = (float*)wsp; wsp += (size_t)G3*64*sizeof(float);        // 768 KB
  float* hF0 = (float*)wsp; wsp += (size_t)Hz*64*sizeof(float);        // 256 KB
  float* hF1 = (float*)wsp; wsp += (size_t)Hz*64*sizeof(float);        // 256 KB
  float* iT  = (float*)wsp; wsp += (size_t)Hz*64*sizeof(float);        // 256 KB
  unsigned short* hB0 = (unsigned short*)wsp; wsp += (size_t)Bz*Hz*2;  // 128 KB
  unsigned short* hB1 = (unsigned short*)wsp; wsp += (size_t)Bz*Hz*2;  // 128 KB
  unsigned short* rhB = (unsigned short*)wsp; wsp += (size_t)Bz*Hz*2;  // 128 KB
  int* canP = (int*)wsp; wsp += 512;                                   // canP[64] + canH[64]
  int* canH = canP + 64;
  unsigned short* igT = (unsigned short*)wsp;                          // 96 MB

  hipMemsetAsync(canP, 0, 512, stream);
  kP  <<<dim3(G3/16),   256,  0, stream>>>(ctx, Wp, bp, bh, bc, bi, pT);
  kI  <<<dim3(64),      256,  0, stream>>>(h0, hF0, hB0);
  kAm <<<dim3(48,16),   1024, 0, stream>>>(x, Wi, pT, igT);
  krec<<<dim3(NBK),     1024, 0, stream>>>(Wh, Wc, igT, hF0, hF1, hB0, hB1, rhB, iT, out, canP, canH);
  ktr <<<dim3(64),      256,  0, stream>>>(hF0, out + (size_t)Bz*Tz*Hz);
}

// Round 10
// 3971.846 us; speedup vs baseline: 1.2142x; 1.2142x over previous
//
#include <hip/hip_runtime.h>
#include <hip/hip_bf16.h>
#include <math.h>

#define Bz 64
#define Tz 256
#define Dz 512
#define Hz 1024
#define G3 3072
#define NBK 64      // blocks in persistent recurrence kernel

typedef short bf16x8 __attribute__((ext_vector_type(8)));
typedef float f32x4 __attribute__((ext_vector_type(4)));

__device__ __forceinline__ float sigm(float x){ return 1.0f/(1.0f+expf(-x)); }

__device__ __forceinline__ unsigned short f2b(float f){
  union{float f;unsigned u;}v; v.f=f;
  unsigned r = v.u + 0x7FFFu + ((v.u>>16)&1u);
  return (unsigned short)(r>>16);
}
__device__ __forceinline__ float b2f(unsigned short s){
  union{unsigned u;float f;}v; v.u = ((unsigned)s)<<16; return v.f;
}
__device__ __forceinline__ unsigned pk2(float a, float b){
  return (unsigned)f2b(a) | ((unsigned)f2b(b)<<16);
}

// ---- coherence protocol (rounds 5/6/8/9 lessons) ----
// PRODUCER: shared-state writes via relaxed sc1 atomic stores (bypass L1/L2,
//   land at memory-side LLC). __syncthreads drains vmcnt, tid0 stores flag.
// CONSUMER: per-wave subset poll (relaxed), NO inv. Bulk B-operands via
//   inline-asm global_load_dwordx4 sc0 sc1 (LLC-direct) at DEDUPLICATED
//   volume (r9 lesson: bypass costs ~2x cached+inv only when reads repeat).
//   Small hF/iT reads via 8B relaxed agent atomics. Plain cached reads only
//   for immutable data (igT, weights).
__device__ __forceinline__ unsigned long long cld64(const void* p){
  return __hip_atomic_load((const unsigned long long*)p, __ATOMIC_RELAXED, __HIP_MEMORY_SCOPE_AGENT);
}
__device__ __forceinline__ void cst64(void* p, unsigned long long v){
  __hip_atomic_store((unsigned long long*)p, v, __ATOMIC_RELAXED, __HIP_MEMORY_SCOPE_AGENT);
}
__device__ __forceinline__ float2 cldf2(const float* p){
  union { unsigned long long u; float2 f; } U; U.u = cld64(p); return U.f;
}
__device__ __forceinline__ void cstf2(float* p, float a, float b){
  union { unsigned long long u; float2 f; } U; U.f = make_float2(a,b); cst64(p, U.u);
}
__device__ __forceinline__ int cld32(const int* p){
  return __hip_atomic_load(p, __ATOMIC_RELAXED, __HIP_MEMORY_SCOPE_AGENT);
}
__device__ __forceinline__ void cst32(int* p, int v){
  __hip_atomic_store(p, v, __ATOMIC_RELAXED, __HIP_MEMORY_SCOPE_AGENT);
}

// ---------------- f32 skinny GEMM core (kP only, tiny) ----------------
#define KCHUNK 128
#define LDA 132
template<int COLS, int KDIM>
__device__ __forceinline__ void gemm_core(const float* __restrict__ Abase, int rowStride,
                                          const float* __restrict__ W,
                                          int jc0, int b, int tid,
                                          float* __restrict__ acc, float* __restrict__ lds)
{
#pragma unroll
  for (int c=0;c<COLS;c++) acc[c]=0.0f;
  constexpr int C4 = KCHUNK/4;
  for (int kb=0; kb<KDIM; kb+=KCHUNK) {
    __syncthreads();
    for (int i = tid; i < Bz*C4; i += 256) {
      int r  = i / C4;
      int c4 = i % C4;
      float4 v = *(const float4*)(Abase + (size_t)r*rowStride + kb + c4*4);
      *(float4*)(lds + r*LDA + c4*4) = v;
    }
    __syncthreads();
    const float* arow  = lds + b*LDA;
    const float* wbase = W + (size_t)jc0*KDIM + kb;
    for (int k=0;k<KCHUNK;k+=4) {
      float4 a = *(const float4*)(arow + k);
#pragma unroll
      for (int c=0;c<COLS;c++) {
        float4 w = *(const float4*)(wbase + (size_t)c*KDIM + k);
        acc[c] = fmaf(a.x,w.x,fmaf(a.y,w.y,fmaf(a.z,w.z,fmaf(a.w,w.w,acc[c]))));
      }
    }
  }
}

// ---- kP: pT[j][b] = ctx[b]·Wp[j] + bp[j] + bi[j] + (j<2H ? bh[j] : bc[j-2H])
__global__ __launch_bounds__(256)
void kP(const float* __restrict__ ctx, const float* __restrict__ Wp,
        const float* __restrict__ bp, const float* __restrict__ bh,
        const float* __restrict__ bc, const float* __restrict__ bi,
        float* __restrict__ pT)
{
  __shared__ float lds[Bz*LDA];
  int tid=threadIdx.x; int b=tid&63;
  int wv=__builtin_amdgcn_readfirstlane(tid>>6);
  int jc0 = blockIdx.x*16 + wv*4;
  float acc[4];
  gemm_core<4, Hz>(ctx, Hz, Wp, jc0, b, tid, acc, lds);
#pragma unroll
  for(int c=0;c<4;c++){
    int j=jc0+c;
    float v = acc[c] + bp[j] + bi[j] + (j < 2*Hz ? bh[j] : bc[j-2*Hz]);
    pT[(size_t)j*64 + b] = v;
  }
}

// ---- kI: hF quad-layout init + hB bf16 init (parity-0 buffers). 64 blocks x 256 thr.
__global__ __launch_bounds__(256)
void kI(const float* __restrict__ h0, float* __restrict__ hF, unsigned short* __restrict__ hB)
{
  int b = blockIdx.x;
  int j = threadIdx.x*4;
  float4 v = *(const float4*)(h0 + (size_t)b*Hz + j);
  *(float4*)(hF + ((size_t)(j>>2)*64 + b)*4) = v;
  unsigned long long pk = (unsigned long long)pk2(v.x,v.y)
                        | ((unsigned long long)pk2(v.z,v.w) << 32);
  *(unsigned long long*)(hB + (size_t)b*Hz + j) = pk;
}

// ---- kAm: MFMA input GEMM. igT[t][j][b] = bf16( x[b,t]·Wi[j] + pT[j][b] )
__global__ __launch_bounds__(1024)
void kAm(const float* __restrict__ x, const float* __restrict__ Wi,
         const float* __restrict__ pT, unsigned short* __restrict__ igT)
{
  __shared__ unsigned short wiF[4*16*64*8];  // 64 KB
  __shared__ unsigned short xs[64*528];      // 66 KB
  __shared__ unsigned short igs[64*64];      // 8 KB
  const int tid = threadIdx.x;
  const int lane = tid & 63;
  const int w = __builtin_amdgcn_readfirstlane(tid >> 6);
  const int j0 = blockIdx.x * 64;
  const int t0 = blockIdx.y * 16;
  const int mt = w >> 2, nt = w & 3;
  const int bb = nt*16 + (lane & 15);
  const int q  = lane >> 4;
  const int jl = mt*16 + q*4;

  for (int idx = tid; idx < 4096; idx += 1024) {
    int mt2 = idx >> 10;
    int ks = (idx >> 6) & 15;
    int ln = idx & 63;
    int j = j0 + mt2*16 + (ln & 15);
    int k = ks*32 + (ln >> 4)*8;
    const float* s = Wi + (size_t)j*Dz + k;
    unsigned short* d = wiF + (size_t)idx*8;
#pragma unroll
    for (int qq=0;qq<8;qq++) d[qq] = f2b(s[qq]);
  }
  float pv[4];
#pragma unroll
  for (int r=0;r<4;r++) pv[r] = pT[(size_t)(j0+jl+r)*64 + bb];

  for (int it=0; it<16; it++) {
    int t = t0 + it;
    __syncthreads();
    for (int i = tid; i < 64*32; i += 1024) {
      int b = i >> 5, c = i & 31;
      const float* s = x + ((size_t)b*Tz + t)*Dz + c*16;
      unsigned* d = (unsigned*)(xs + (size_t)b*528 + c*16);
      float4 v0 = *(const float4*)(s);
      float4 v1 = *(const float4*)(s+4);
      float4 v2 = *(const float4*)(s+8);
      float4 v3 = *(const float4*)(s+12);
      d[0]=pk2(v0.x,v0.y); d[1]=pk2(v0.z,v0.w);
      d[2]=pk2(v1.x,v1.y); d[3]=pk2(v1.z,v1.w);
      d[4]=pk2(v2.x,v2.y); d[5]=pk2(v2.z,v2.w);
      d[6]=pk2(v3.x,v3.y); d[7]=pk2(v3.z,v3.w);
    }
    __syncthreads();
    f32x4 acc = {0.f,0.f,0.f,0.f};
    const unsigned short* bsrc = xs + (size_t)bb*528 + q*8;
#pragma unroll
    for (int ks=0; ks<16; ks++) {
      bf16x8 a = *(const bf16x8*)(wiF + ((size_t)(mt*16+ks)*64 + lane)*8);
      bf16x8 b = *(const bf16x8*)(bsrc + ks*32);
      acc = __builtin_amdgcn_mfma_f32_16x16x32_bf16(a, b, acc, 0, 0, 0);
    }
#pragma unroll
    for (int r=0;r<4;r++) igs[(size_t)(jl+r)*64 + bb] = f2b(acc[r] + pv[r]);
    __syncthreads();
    if (tid < 512) {
      int j = tid >> 3, seg = tid & 7;
      *(uint4*)(igT + ((size_t)t*G3 + j0 + j)*64 + seg*8) =
        *(const uint4*)(igs + (size_t)j*64 + seg*8);
    }
  }
}

// ---- krec: persistent MFMA recurrence, 64 blocks x 1024 threads.
// Per-wave producer-subset waits + LLC-direct deduplicated B reads (no inv).
// Phase1: 16 waves = 4 col-tile-pairs(nt, both mt) x split-K-4(kh); wave (nt,kh)
//   waits only canH[kh*16..kh*16+15] (the producers of its k-slice).
// Phase2: 16 waves = 4(nt) x split-K-4(kq); wave waits canP[kq*8..kq*8+7];
//   wave 0 lanes 56-63 also cover the iT producer (block 32+n/2).
// Epilogue (sole writer of rhB/iT/hF/hB) runs after the block-wide barrier =
//   after the UNION of all subsets (all producers) -> WAR-safe as before.
// hF/hB parity double-buffered; rhB/iT single-buffered (canH/canP chain).
__global__ __launch_bounds__(1024)
void krec(const float* __restrict__ Wh, const float* __restrict__ Wc,
          const unsigned short* __restrict__ igT,
          float* __restrict__ hF0, float* __restrict__ hF1,
          unsigned short* __restrict__ hB0, unsigned short* __restrict__ hB1,
          unsigned short* __restrict__ rhB, float* __restrict__ iT,
          float* __restrict__ out, int* canP, int* canH)
{
  __shared__ unsigned short whF[2*32*64*8];  // 64 KB
  __shared__ unsigned short wcF[32*64*8];    // 32 KB
  __shared__ float red[32*64*4];             // 32 KB (phase1: 32 tile-slots)
  const int tid = threadIdx.x;
  const int lane = tid & 63;
  const int w = __builtin_amdgcn_readfirstlane(tid >> 6);
  const int n = blockIdx.x;

  // fragment-swizzle weight slices (f32 -> bf16), one-time
  for (int idx = tid; idx < 4096; idx += 1024) {
    int mt = idx >> 11;
    int ks = (idx >> 6) & 31;
    int ln = idx & 63;
    int j = n*32 + mt*16 + (ln & 15);
    int k = ks*32 + (ln >> 4)*8;
    const float* s = Wh + (size_t)j*Hz + k;
    unsigned short* d = whF + (size_t)idx*8;
#pragma unroll
    for (int qq=0;qq<8;qq++) d[qq] = f2b(s[qq]);
  }
  for (int idx = tid; idx < 2048; idx += 1024) {
    int ks = (idx >> 6) & 31;
    int ln = idx & 63;
    int j = n*16 + (ln & 15);
    int k = ks*32 + (ln >> 4)*8;
    const float* s = Wc + (size_t)j*Hz + k;
    unsigned short* d = wcF + (size_t)idx*8;
#pragma unroll
    for (int qq=0;qq<8;qq++) d[qq] = f2b(s[qq]);
  }

  const int nt = w & 3;            // col-tile / batch-tile index (both phases)
  const int kh = w >> 2;           // split-K-4 index (both phases)
  const int bb = nt*16 + (lane & 15);
  const int q  = lane >> 4;

  for (int t=0;t<Tz;t++) {
    const unsigned short* igt = igT + (size_t)t*G3*64;
    const unsigned short* hBr = (t&1) ? hB1 : hB0;
    unsigned short*       hBw = (t&1) ? hB0 : hB1;
    const float*          hFr = (t&1) ? hF1 : hF0;
    float*                hFw = (t&1) ? hF0 : hF1;
    // ---------- phase 1: gates r,i (each wave: both mt tiles, k-slice kh) ----------
    {
      float igv[4];
      if (w < 8) {                        // epilogue tile (emt=w>>2, ent=w&3) prefetch
        int jg = n*32 + (w>>2)*16 + q*4;
#pragma unroll
        for (int r=0;r<4;r++) igv[r] = b2f(igt[(size_t)(jg+r)*64 + bb]);
      }
      // per-wave wait: producers of k-slice [kh*256, kh*256+256) = blocks kh*16..+16
      {
        const int* p = canH + kh*16 + (lane & 15);
        while (!__all(cld32(p) >= t)) __builtin_amdgcn_s_sleep(2);
        asm volatile("" ::: "memory");
      }
      bf16x8 bfr[8];
      {
        unsigned voff = (unsigned)(bb*2048 + q*16 + kh*512);
        asm volatile(
          "global_load_dwordx4 %0, %8, %9 sc0 sc1\n\t"
          "global_load_dwordx4 %1, %8, %9 offset:64 sc0 sc1\n\t"
          "global_load_dwordx4 %2, %8, %9 offset:128 sc0 sc1\n\t"
          "global_load_dwordx4 %3, %8, %9 offset:192 sc0 sc1\n\t"
          "global_load_dwordx4 %4, %8, %9 offset:256 sc0 sc1\n\t"
          "global_load_dwordx4 %5, %8, %9 offset:320 sc0 sc1\n\t"
          "global_load_dwordx4 %6, %8, %9 offset:384 sc0 sc1\n\t"
          "global_load_dwordx4 %7, %8, %9 offset:448 sc0 sc1\n\t"
          "s_waitcnt vmcnt(0)"
          : "=v"(bfr[0]), "=v"(bfr[1]), "=v"(bfr[2]), "=v"(bfr[3]),
            "=v"(bfr[4]), "=v"(bfr[5]), "=v"(bfr[6]), "=v"(bfr[7])
          : "v"(voff), "s"(hBr)
          : "memory");
      }
      f32x4 acc0 = {0.f,0.f,0.f,0.f}, acc1 = {0.f,0.f,0.f,0.f};
      const unsigned short* a0 = whF + ((size_t)(kh*8)*64 + lane)*8;        // mt=0
      const unsigned short* a1 = whF + ((size_t)(32 + kh*8)*64 + lane)*8;   // mt=1
#pragma unroll
      for (int ks=0; ks<8; ks++) {
        bf16x8 A0 = *(const bf16x8*)(a0 + (size_t)ks*512);
        bf16x8 A1 = *(const bf16x8*)(a1 + (size_t)ks*512);
        acc0 = __builtin_amdgcn_mfma_f32_16x16x32_bf16(A0, bfr[ks], acc0, 0, 0, 0);
        acc1 = __builtin_amdgcn_mfma_f32_16x16x32_bf16(A1, bfr[ks], acc1, 0, 0, 0);
      }
      *(f32x4*)(red + ((size_t)((kh*4+nt)*2+0)*64 + lane)*4) = acc0;
      *(f32x4*)(red + ((size_t)((kh*4+nt)*2+1)*64 + lane)*4) = acc1;
      __syncthreads();
      if (w < 8) {
        int emt = w >> 2, ent = w & 3;
        int jg = n*32 + emt*16 + q*4;     // bb for ent == bb (ent == nt for w<8)
        f32x4 s = {0.f,0.f,0.f,0.f};
#pragma unroll
        for (int kk=0; kk<4; kk++) {
          f32x4 v = *(const f32x4*)(red + ((size_t)((kk*4+ent)*2+emt)*64 + lane)*4);
          s[0]+=v[0]; s[1]+=v[1]; s[2]+=v[2]; s[3]+=v[3];
        }
        if (n < 32) {
          const float* hp = hFr + ((size_t)(jg>>2)*64 + bb)*4;
          float2 a01 = cldf2(hp), a23 = cldf2(hp+2);   // LLC-direct
          float hv[4] = {a01.x, a01.y, a23.x, a23.y};
          unsigned long long pk = 0;
#pragma unroll
          for (int r=0;r<4;r++) {
            float g = sigm(s[r] + igv[r]);
            pk |= (unsigned long long)f2b(g * hv[r]) << (16*r);
          }
          cst64(rhB + (size_t)bb*Hz + jg, pk);          // sc1 -> LLC
        } else {
          float g0 = sigm(s[0] + igv[0]);
          float g1 = sigm(s[1] + igv[1]);
          float g2 = sigm(s[2] + igv[2]);
          float g3 = sigm(s[3] + igv[3]);
          float* ip = iT + ((size_t)((jg-1024)>>2)*64 + bb)*4;
          cstf2(ip, g0, g1); cstf2(ip+2, g2, g3);       // sc1 -> LLC
        }
      }
      __syncthreads();                    // vmcnt drained -> sc1 stores at LLC
      if (tid == 0) cst32(canP + n, t+1); // relaxed flag
    }
    // ---------- phase 2: n-gate + h update ----------
    {
      float igv[4];
      if (w < 4) {
        int jn = n*16 + q*4;
#pragma unroll
        for (int r=0;r<4;r++) igv[r] = b2f(igt[(size_t)(2048+jn+r)*64 + bb]);
      }
      // per-wave wait: rhB producers kq*8..+8; wave 0 lanes 56-63 cover iT producer
      {
        int pi = kh*8 + (lane & 7);
        if (w == 0 && lane >= 56) pi = 32 + (n >> 1);
        const int* p = canP + pi;
        while (!__all(cld32(p) >= t+1)) __builtin_amdgcn_s_sleep(2);
        asm volatile("" ::: "memory");
      }
      bf16x8 bfr[8];
      {
        unsigned voff = (unsigned)(bb*2048 + q*16 + kh*512);
        asm volatile(
          "global_load_dwordx4 %0, %8, %9 sc0 sc1\n\t"
          "global_load_dwordx4 %1, %8, %9 offset:64 sc0 sc1\n\t"
          "global_load_dwordx4 %2, %8, %9 offset:128 sc0 sc1\n\t"
          "global_load_dwordx4 %3, %8, %9 offset:192 sc0 sc1\n\t"
          "global_load_dwordx4 %4, %8, %9 offset:256 sc0 sc1\n\t"
          "global_load_dwordx4 %5, %8, %9 offset:320 sc0 sc1\n\t"
          "global_load_dwordx4 %6, %8, %9 offset:384 sc0 sc1\n\t"
          "global_load_dwordx4 %7, %8, %9 offset:448 sc0 sc1\n\t"
          "s_waitcnt vmcnt(0)"
          : "=v"(bfr[0]), "=v"(bfr[1]), "=v"(bfr[2]), "=v"(bfr[3]),
            "=v"(bfr[4]), "=v"(bfr[5]), "=v"(bfr[6]), "=v"(bfr[7])
          : "v"(voff), "s"(rhB)
          : "memory");
      }
      f32x4 acc = {0.f,0.f,0.f,0.f};
#pragma unroll
      for (int ks=0; ks<8; ks++) {
        bf16x8 a = *(const bf16x8*)(wcF + ((size_t)(kh*8+ks)*64 + lane)*8);
        acc = __builtin_amdgcn_mfma_f32_16x16x32_bf16(a, bfr[ks], acc, 0, 0, 0);
      }
      *(f32x4*)(red + ((size_t)w*64 + lane)*4) = acc;
      __syncthreads();
      if (w < 4) {
        f32x4 s0 = *(const f32x4*)(red + ((size_t)w*64+lane)*4);
        f32x4 s1 = *(const f32x4*)(red + ((size_t)(w+4)*64+lane)*4);
        f32x4 s2 = *(const f32x4*)(red + ((size_t)(w+8)*64+lane)*4);
        f32x4 s3 = *(const f32x4*)(red + ((size_t)(w+12)*64+lane)*4);
        int jn = n*16 + q*4;
        const float* hp = hFr + ((size_t)(jn>>2)*64 + bb)*4;
        float2 a01 = cldf2(hp), a23 = cldf2(hp+2);     // own sc1 data
        float hv[4] = {a01.x, a01.y, a23.x, a23.y};
        const float* ip = iT + ((size_t)(jn>>2)*64 + bb)*4;
        float2 b01 = cldf2(ip), b23 = cldf2(ip+2);     // cross-block (flag covered)
        float iv[4] = {b01.x, b01.y, b23.x, b23.y};
        float hy4[4];
        unsigned long long pk = 0;
#pragma unroll
        for (int r=0;r<4;r++) {
          float g  = s0[r]+s1[r]+s2[r]+s3[r] + igv[r];
          float ng = tanhf(g);
          float hy = hv[r] + iv[r]*(ng - hv[r]);
          hy4[r] = hy;
          pk |= (unsigned long long)f2b(hy) << (16*r);
        }
        float* hpw = hFw + ((size_t)(jn>>2)*64 + bb)*4;
        cstf2(hpw,   hy4[0], hy4[1]);                  // sc1 -> LLC
        cstf2(hpw+2, hy4[2], hy4[3]);
        cst64(hBw + (size_t)bb*Hz + jn, pk);           // sc1 -> LLC
        float4 ov; ov.x=hy4[0]; ov.y=hy4[1]; ov.z=hy4[2]; ov.w=hy4[3];
        *(float4*)(out + ((size_t)bb*Tz + t)*Hz + jn) = ov;  // plain (host-only)
      }
      __syncthreads();                    // vmcnt drained -> sc1 stores at LLC
      if (tid == 0) cst32(canH + n, t+1); // relaxed flag
    }
  }
}

// ---- final hidden state: hN[b][j] = hF(quad)[j][b]
__global__ __launch_bounds__(256)
void ktr(const float* __restrict__ hF, float* __restrict__ hN)
{
  int b = blockIdx.x;
  int j = threadIdx.x*4;
  float4 v = *(const float4*)(hF + ((size_t)(j>>2)*64 + b)*4);
  *(float4*)(hN + (size_t)b*Hz + j) = v;
}

extern "C" void kernel_launch(void* const* d_in, const int* in_sizes, int n_in,
                              void* d_out, int out_size, void* d_ws, size_t ws_size,
                              hipStream_t stream)
{
  const float* x   = (const float*)d_in[0];
  const float* h0  = (const float*)d_in[1];
  const float* ctx = (const float*)d_in[2];
  const float* Wi  = (const float*)d_in[3];
  const float* bi  = (const float*)d_in[4];
  const float* Wh  = (const float*)d_in[5];
  const float* bh  = (const float*)d_in[6];
  const float* Wp  = (const float*)d_in[7];
  const float* bp  = (const float*)d_in[8];
  const float* Wc  = (const float*)d_in[9];
  const float* bc  = (const float*)d_in[10];
  float* out = (float*)d_out;

  char* wsp = (char*)d_ws;
  float* pT  = (float*)wsp; wsp += (size_t)G3*64*sizeof(float);        // 768 KB
  float* hF0 = (float*)wsp; wsp += (size_t)Hz*64*sizeof(float);        // 256 KB
  float* hF1 = (float*)wsp; wsp += (size_t)Hz*64*sizeof(float);        // 256 KB
  float* iT  = (float*)wsp; wsp += (size_t)Hz*64*sizeof(float);        // 256 KB
  unsigned short* hB0 = (unsigned short*)wsp; wsp += (size_t)Bz*Hz*2;  // 128 KB
  unsigned short* hB1 = (unsigned short*)wsp; wsp += (size_t)Bz*Hz*2;  // 128 KB
  unsigned short* rhB = (unsigned short*)wsp; wsp += (size_t)Bz*Hz*2;  // 128 KB
  int* canP = (int*)wsp; wsp += 512;                                   // canP[64] + canH[64]
  int* canH = canP + 64;
  unsigned short* igT = (unsigned short*)wsp;                          // 96 MB

  hipMemsetAsync(canP, 0, 512, stream);
  kP  <<<dim3(G3/16),   256,  0, stream>>>(ctx, Wp, bp, bh, bc, bi, pT);
  kI  <<<dim3(64),      256,  0, stream>>>(h0, hF0, hB0);
  kAm <<<dim3(48,16),   1024, 0, stream>>>(x, Wi, pT, igT);
  krec<<<dim3(NBK),     1024, 0, stream>>>(Wh, Wc, igT, hF0, hF1, hB0, hB1, rhB, iT, out, canP, canH);
  ktr <<<dim3(64),      256,  0, stream>>>(hF0, out + (size_t)Bz*Tz*Hz);
}